// Round 8
// baseline (41.758 us; speedup 1.0000x reference)
//
#include <hip/hip_runtime.h>

typedef float f4 __attribute__((ext_vector_type(4)));
typedef f4 __attribute__((aligned(4))) f4u;     // 4B-aligned 16B store (gfx950 HW-ok)
typedef float f2 __attribute__((ext_vector_type(2)));
typedef f2 __attribute__((aligned(4))) f2u;

#define NJ 24
#define BLK 128
#define OUTW 75               // (NJ+1)*3 floats per row

// broadcast lane j's float to all lanes as a wave-uniform (SGPR) value
#define RL(v, j) __int_as_float(__builtin_amdgcn_readlane(__float_as_int(v), (j)))

__global__ __launch_bounds__(BLK, 4) void fk_main_kernel(
    const float* __restrict__ ang,   // (B, 24)
    const float* __restrict__ xyz,   // (24, 3)
    const float* __restrict__ rpy,   // (24, 3)
    const float* __restrict__ axis,  // (24, 3)
    float* __restrict__ out)         // (B, 75)
{
    const int tid = threadIdx.x;
    const int ln  = tid & 63;

    // ---- my row's 24 angles via 6x float4 (row base 96B -> 16B aligned) ----
    const long long row = (long long)blockIdx.x * BLK + tid;
    const f4* gA = (const f4*)(ang + row * NJ);
    f4 A[6];
    #pragma unroll
    for (int k = 0; k < 6; ++k) A[k] = gA[k];

    // ---- per-joint constants: lanes 0..23 of EACH wave hold joint ln's 12 ----
    float c0=0,c1=0,c2=0,c3=0,c4=0,c5=0,c6=0,c7=0,c8=0,c9=0,c10=0,c11=0;
    if (ln < NJ) {
        const int j = ln;
        float r = rpy[j*3+0] * 0.5f, p = rpy[j*3+1] * 0.5f, yv = rpy[j*3+2] * 0.5f;
        float sr, cr, sp, cp, sy, cy;
        __sincosf(r, &sr, &cr);
        __sincosf(p, &sp, &cp);
        __sincosf(yv, &sy, &cy);
        float qw = cr*cp*cy + sr*sp*sy;
        float qx = sr*cp*cy - cr*sp*sy;
        float qy = cr*sp*cy + sr*cp*sy;
        float qz = cr*cp*sy - sr*sp*cy;
        float ax = axis[j*3+0], ay = axis[j*3+1], az = axis[j*3+2];
        float n = sqrtf(ax*ax + ay*ay + az*az);
        float inv = 1.0f / fmaxf(n, 1e-6f);
        float ux = ax*inv, uy = ay*inv, uz = az*inv;
        c0 = qw; c1 = qx; c2 = qy; c3 = qz;            // qA = qRo
        c4 = -(qx*ux + qy*uy + qz*uz);                  // qB = qRo x (0,u)
        c5 = qw*ux + qy*uz - qz*uy;
        c6 = qw*uy + qz*ux - qx*uz;
        c7 = qw*uz + qx*uy - qy*ux;
        c8 = xyz[j*3+0]; c9 = xyz[j*3+1]; c10 = xyz[j*3+2];
        c11 = n * 0.5f;
    }

    // ---- FK scan: quat chain, positions accumulate in registers ----
    float o[OUTW];                       // all indices compile-time -> VGPRs
    o[0] = 0.f; o[1] = 0.f; o[2] = 0.f;
    float Qw = 1.f, Qx = 0.f, Qy = 0.f, Qz = 0.f;
    float t0 = 0.f, t1 = 0.f, t2 = 0.f;

    #pragma unroll
    for (int j = 0; j < NJ; ++j) {
        // wave-uniform consts for joint j via readlane -> SGPRs
        float qa0 = RL(c0, j), qa1 = RL(c1, j), qa2 = RL(c2, j), qa3 = RL(c3, j);
        float qb0 = RL(c4, j), qb1 = RL(c5, j), qb2 = RL(c6, j), qb3 = RL(c7, j);
        float vx  = RL(c8, j), vy  = RL(c9, j), vz  = RL(c10, j);
        float hn  = RL(c11, j);

        float h = A[j >> 2][j & 3] * hn;
        float s, cq;
        __sincosf(h, &s, &cq);
        float lw = cq*qa0 + s*qb0;
        float lx = cq*qa1 + s*qb1;
        float ly = cq*qa2 + s*qb2;
        float lz = cq*qa3 + s*qb3;
        // t += rotate(Q_parent, v)
        float px = Qy*vz - Qz*vy + Qw*vx;
        float py = Qz*vx - Qx*vz + Qw*vy;
        float pz = Qx*vy - Qy*vx + Qw*vz;
        t0 += vx + 2.0f*(Qy*pz - Qz*py);
        t1 += vy + 2.0f*(Qz*px - Qx*pz);
        t2 += vz + 2.0f*(Qx*py - Qy*px);
        // Q = Q (x) q_loc
        float nw = Qw*lw - Qx*lx - Qy*ly - Qz*lz;
        float nx = Qw*lx + Qx*lw + Qy*lz - Qz*ly;
        float ny = Qw*ly - Qx*lz + Qy*lw + Qz*lx;
        float nz = Qw*lz + Qx*ly - Qy*lx + Qz*lw;
        Qw = nw; Qx = nx; Qy = ny; Qz = nz;
        o[3*(j+1)+0] = t0;
        o[3*(j+1)+1] = t1;
        o[3*(j+1)+2] = t2;
    }

    // ---- one contiguous 300B burst per thread: full line coverage, no LDS ----
    float* gR = out + row * OUTW;
    #pragma unroll
    for (int k = 0; k < 18; ++k) {
        f4 v = { o[4*k+0], o[4*k+1], o[4*k+2], o[4*k+3] };
        *(f4u*)(gR + 4*k) = v;
    }
    { f2 v = { o[72], o[73] }; *(f2u*)(gR + 72) = v; }
    gR[74] = o[74];
}

extern "C" void kernel_launch(void* const* d_in, const int* in_sizes, int n_in,
                              void* d_out, int out_size, void* d_ws, size_t ws_size,
                              hipStream_t stream) {
    const float* ang  = (const float*)d_in[0];
    const float* xyz  = (const float*)d_in[1];
    const float* rpy  = (const float*)d_in[2];
    const float* axis = (const float*)d_in[3];
    float* out = (float*)d_out;

    const int B = in_sizes[0] / NJ;          // 262144
    const int grid = B / BLK;                // 2048 = 8 blocks/CU, one round
    fk_main_kernel<<<grid, BLK, 0, stream>>>(ang, xyz, rpy, axis, out);
}